// Round 8
// baseline (1789.310 us; speedup 1.0000x reference)
//
#include <hip/hip_runtime.h>
#include <hip/hip_bf16.h>

// Problem constants (from reference)
#define FEAT 64          // IN_F = HID_F = OUT_F
#define CAT_F 128        // HID_F + IN_F
#define CAP   64         // ELL capacity; deg ~ Poisson(10), P(deg>64) ~ 0

// bf16 helpers: u32 holds 2 bf16 (low ushort = even elem, high = odd elem)
__device__ inline float blo(unsigned u) { union { unsigned x; float f; } v; v.x = u << 16; return v.f; }
__device__ inline float bhi(unsigned u) { union { unsigned x; float f; } v; v.x = u & 0xFFFF0000u; return v.f; }
__device__ inline unsigned short f2b(float f) {
    union { float f; unsigned u; } v; v.f = f;
    unsigned r = v.u + 0x7FFFu + ((v.u >> 16) & 1u);
    return (unsigned short)(r >> 16);
}
__device__ inline unsigned pk2(float lo, float hi) {
    return (unsigned)f2b(lo) | ((unsigned)f2b(hi) << 16);
}

// ---------------------------------------------------------------------------
__global__ void detect_kernel(const unsigned int* ei, int* mode) {
    *mode = (ei[1] == 0u && ei[3] == 0u && ei[5] == 0u && ei[7] == 0u) ? 1 : 0;
}

// batch convert + root boundaries (batch is sorted; every graph non-empty)
__global__ void batch_prep(const void* __restrict__ bt, const int* __restrict__ mode,
                           int* __restrict__ batch32, int* __restrict__ root_idx,
                           int N, int G) {
    int i = blockIdx.x * blockDim.x + threadIdx.x;
    if (i >= N) return;
    int m = *mode;
    int b = m ? (int)((const long long*)bt)[i] : ((const int*)bt)[i];
    batch32[i] = b;
    if (i == 0) { root_idx[0] = 0; root_idx[G] = N; }
    else {
        int bp = m ? (int)((const long long*)bt)[i - 1] : ((const int*)bt)[i - 1];
        if (b != bp) root_idx[b] = i;
    }
}

// ---------------------------------------------------------------------------
// Register-tiled GEMM body (shared): 64x64 tile, 256 threads, 4x4 micro-tile.
// fp32 LDS staging, k-split (two 32-k halves) to keep LDS at 24.7 KB.
// Output: hq blocked bf16 [4][N][16], optionally prescaled by dis[row].
template <int RELU_A, int ADDV, int PRESCALE>
__device__ void gemm_body(int bid, const float* __restrict__ A, const float* __restrict__ B,
                          const float* __restrict__ addv, const int* __restrict__ batch32,
                          const float* __restrict__ dis, unsigned short* __restrict__ hq,
                          int N, float (*AsT)[68], float (*Bs)[64]) {
    const int tid = threadIdx.x;
    const long base = (long)bid * 64;
#pragma unroll
    for (int u = 0; u < 4; ++u) {             // stage B fully (64x64)
        int v = tid + u * 256, row = v >> 4, c4 = (v & 15) * 4;
        *(float4*)&Bs[row][c4] = *(const float4*)&B[row * 64 + c4];
    }
    const int c0 = (tid & 15) * 4, r0 = (tid >> 4) * 4;
    float4 acc0 = make_float4(0.f, 0.f, 0.f, 0.f);
    float4 acc1 = acc0, acc2 = acc0, acc3 = acc0;

#pragma unroll
    for (int h = 0; h < 2; ++h) {             // k-split halves
        __syncthreads();
#pragma unroll
        for (int u = 0; u < 2; ++u) {         // stage A half transposed
            int v = tid + u * 256, row = v >> 3, c4 = (v & 7) * 4;
            float4 av = make_float4(0.f, 0.f, 0.f, 0.f);
            if (base + row < N) av = *(const float4*)&A[(base + row) * 64 + h * 32 + c4];
            if (RELU_A) {
                av.x = fmaxf(av.x, 0.f); av.y = fmaxf(av.y, 0.f);
                av.z = fmaxf(av.z, 0.f); av.w = fmaxf(av.w, 0.f);
            }
            AsT[c4 + 0][row] = av.x; AsT[c4 + 1][row] = av.y;
            AsT[c4 + 2][row] = av.z; AsT[c4 + 3][row] = av.w;
        }
        __syncthreads();
#pragma unroll
        for (int kk = 0; kk < 32; ++kk) {
            float4 bv = *(const float4*)&Bs[h * 32 + kk][c0];
            float4 av = *(const float4*)&AsT[kk][r0];
            acc0.x = fmaf(av.x, bv.x, acc0.x); acc0.y = fmaf(av.x, bv.y, acc0.y);
            acc0.z = fmaf(av.x, bv.z, acc0.z); acc0.w = fmaf(av.x, bv.w, acc0.w);
            acc1.x = fmaf(av.y, bv.x, acc1.x); acc1.y = fmaf(av.y, bv.y, acc1.y);
            acc1.z = fmaf(av.y, bv.z, acc1.z); acc1.w = fmaf(av.y, bv.w, acc1.w);
            acc2.x = fmaf(av.z, bv.x, acc2.x); acc2.y = fmaf(av.z, bv.y, acc2.y);
            acc2.z = fmaf(av.z, bv.z, acc2.z); acc2.w = fmaf(av.z, bv.w, acc2.w);
            acc3.x = fmaf(av.w, bv.x, acc3.x); acc3.y = fmaf(av.w, bv.y, acc3.y);
            acc3.z = fmaf(av.w, bv.z, acc3.z); acc3.w = fmaf(av.w, bv.w, acc3.w);
        }
    }
    const long qbase = (long)(c0 >> 4) * N * 16 + (c0 & 15);
#define STORE_ROW(i, a)                                                       \
    {                                                                         \
        long row = base + r0 + (i);                                           \
        if (row < N) {                                                        \
            if (ADDV) {                                                       \
                int g = batch32[row];                                         \
                float4 adv = *(const float4*)&addv[(long)g * 64 + c0];        \
                a.x += adv.x; a.y += adv.y; a.z += adv.z; a.w += adv.w;       \
            }                                                                 \
            float s = PRESCALE ? dis[row] : 1.0f;                             \
            ushort4 o;                                                        \
            o.x = f2b(s * a.x); o.y = f2b(s * a.y);                           \
            o.z = f2b(s * a.z); o.w = f2b(s * a.w);                           \
            *(ushort4*)&hq[qbase + row * 16] = o;                             \
        }                                                                     \
    }
    STORE_ROW(0, acc0) STORE_ROW(1, acc1) STORE_ROW(2, acc2) STORE_ROW(3, acc3)
#undef STORE_ROW
}

// ---------------------------------------------------------------------------
// MEGA kernel 1: [ell blocks | gemm1 blocks | rootc blocks]
//   ell:   per edge (r,c) r!=c: deg_cnt[r]++, slot=cnt_col[c]++, ell[c][slot]=r
//   gemm1: hq = bf16(x @ w1)   (unscaled; prescale applied after node degrees)
//   rootc: rootc[g] = relu(x[root_g]) @ w2[64:128]
// __launch_bounds__(256,4): 128-VGPR budget — REQUIRED, else the 16 fp32
// accumulators spill to scratch (round-3 and round-7 lesson: 64-VGPR cap ->
// 1.5 GB scratch traffic, 10x slowdown).
__global__ __launch_bounds__(256, 4)
void mega1(const void* __restrict__ ei, const int* __restrict__ mode,
           int* __restrict__ deg_cnt, int* __restrict__ cnt_col,
           int* __restrict__ ell, int E,
           const float* __restrict__ x, const float* __restrict__ w1,
           unsigned short* __restrict__ hq,
           const float* __restrict__ w2hi, const int* __restrict__ root_idx,
           float* __restrict__ rootc, int N, int G, int eb, int gb) {
    __shared__ float AsT[32][68];
    __shared__ float Bs[64][64];
    int bid = blockIdx.x;
    if (bid < eb) {
        int e = bid * 256 + threadIdx.x;
        if (e < E) {
            int r, c;
            if (*mode) {
                const long long* p = (const long long*)ei;
                r = (int)p[e]; c = (int)p[E + e];
            } else {
                const int* p = (const int*)ei;
                r = p[e]; c = p[E + e];
            }
            if (r != c) {
                atomicAdd(&deg_cnt[r], 1);
                int slot = atomicAdd(&cnt_col[c], 1);
                if (slot < CAP) ell[c * CAP + slot] = r;
            }
        }
        return;
    }
    bid -= eb;
    if (bid < gb) {
        gemm_body<0, 0, 0>(bid, x, w1, nullptr, nullptr, nullptr, hq, N, AsT, Bs);
        return;
    }
    bid -= gb;
    int g = (bid * 256 + threadIdx.x) >> 6;
    int f = threadIdx.x & 63;
    if (g >= G) return;
    const float* xr = x + (long)root_idx[g] * 64;
    float acc = 0.f;
#pragma unroll
    for (int k = 0; k < 64; ++k)
        acc = fmaf(fmaxf(xr[k], 0.f), w2hi[k * 64 + f], acc);
    rootc[(long)g * 64 + f] = acc;
}

// gemm2 standalone: hq = bf16(dis * (relu(x2) @ w2lo + rootc[batch]))
__global__ __launch_bounds__(256, 4)
void gemm2_kernel(const float* __restrict__ A, const float* __restrict__ B,
                  const float* __restrict__ addv, const int* __restrict__ batch32,
                  const float* __restrict__ dis, unsigned short* __restrict__ hq, int N) {
    __shared__ float AsT[32][68];
    __shared__ float Bs[64][64];
    gemm_body<1, 1, 1>(blockIdx.x, A, B, addv, batch32, dis, hq, N, AsT, Bs);
}

// dis = (1+deg)^-1/2 ; in-place prescale of the blocked h rows: hq *= dis[node]
// grid (ceil(N/256), 4): blockIdx.y = quarter
__global__ void prep_prescale(const int* __restrict__ deg_cnt,
                              unsigned short* __restrict__ hq,
                              float* __restrict__ dis, int N) {
    int node = blockIdx.x * blockDim.x + threadIdx.x;
    if (node >= N) return;
    int q = blockIdx.y;
    float d = rsqrtf(1.0f + (float)deg_cnt[node]);
    if (q == 0) dis[node] = d;
    unsigned short* row = hq + (long)q * N * 16 + (long)node * 16;
    uint4 a = *(uint4*)row;
    uint4 b = *(uint4*)(row + 8);
    a.x = pk2(d * blo(a.x), d * bhi(a.x));
    a.y = pk2(d * blo(a.y), d * bhi(a.y));
    a.z = pk2(d * blo(a.z), d * bhi(a.z));
    a.w = pk2(d * blo(a.w), d * bhi(a.w));
    b.x = pk2(d * blo(b.x), d * bhi(b.x));
    b.y = pk2(d * blo(b.y), d * bhi(b.y));
    b.z = pk2(d * blo(b.z), d * bhi(b.z));
    b.w = pk2(d * blo(b.w), d * bhi(b.w));
    *(uint4*)row = a;
    *(uint4*)(row + 8) = b;
}

// ---------------------------------------------------------------------------
// Quartered conv1 aggregation pass p (table hq[p] = 3.2 MB -> per-XCD L2 resident):
//   x2[node][p*16+f] = dis[node]*(Sum_e hs_p[row_e][f] + hs_p[node][f]) + b1[f]
// wave per node; lane = slot(16) x fl(4); per edge 4 lanes x uint2 = one 32B sector
__global__ void agg1_pass(const unsigned short* __restrict__ hq, const float* __restrict__ dis,
                          const int* __restrict__ cnt_col, const int* __restrict__ ell,
                          const float* __restrict__ bias, float* __restrict__ x2,
                          int N, int p) {
    int node = (blockIdx.x * blockDim.x + threadIdx.x) >> 6;
    int lane = threadIdx.x & 63;
    if (node >= N) return;
    int slot = lane >> 2, fl = lane & 3;
    int cnt = min(cnt_col[node], CAP);
    const int* row = ell + (long)node * CAP;
    const unsigned short* tab = hq + (long)p * N * 16;
    float4 acc = make_float4(0.f, 0.f, 0.f, 0.f);
    for (int j = slot; j < cnt; j += 16) {
        int r = row[j];
        uint2 hv = *(const uint2*)&tab[(long)r * 16 + fl * 4];
        acc.x += blo(hv.x); acc.y += bhi(hv.x);
        acc.z += blo(hv.y); acc.w += bhi(hv.y);
    }
#pragma unroll
    for (int m = 4; m <= 32; m <<= 1) {
        acc.x += __shfl_xor(acc.x, m, 64);
        acc.y += __shfl_xor(acc.y, m, 64);
        acc.z += __shfl_xor(acc.z, m, 64);
        acc.w += __shfl_xor(acc.w, m, 64);
    }
    if (lane < 4) {
        float dc = dis[node];
        uint2 hv = *(const uint2*)&tab[(long)node * 16 + lane * 4];
        float4 bv = *(const float4*)&bias[p * 16 + lane * 4];
        float4 r;
        r.x = fmaf(dc, acc.x + blo(hv.x), bv.x);
        r.y = fmaf(dc, acc.y + bhi(hv.x), bv.y);
        r.z = fmaf(dc, acc.z + blo(hv.y), bv.z);
        r.w = fmaf(dc, acc.w + bhi(hv.y), bv.w);
        *(float4*)&x2[(long)node * 64 + p * 16 + lane * 4] = r;
    }
}

// Quartered conv2 aggregation pass p fused with per-graph mean + root concat:
//   out[g][p*16+f]    = mean_n relu(dis[n]*(Sum_e hs_p[r][f] + hs_p[n][f]) + b2[f])
//   out[g][64+p*16+f] = x2[root_g][p*16+f]
// block (512 thr = 8 waves) per graph
__global__ __launch_bounds__(512)
void agg2_pass(const unsigned short* __restrict__ hq, const float* __restrict__ dis,
               const int* __restrict__ cnt_col, const int* __restrict__ ell,
               const float* __restrict__ bias, const int* __restrict__ root_idx,
               const float* __restrict__ x2, float* __restrict__ out, int N, int p) {
    __shared__ float ls[8][16];
    int g = blockIdx.x;
    int root = root_idx[g], nend = root_idx[g + 1];
    int wid = threadIdx.x >> 6, lane = threadIdx.x & 63;
    int slot = lane >> 2, fl = lane & 3;
    const unsigned short* tab = hq + (long)p * N * 16;
    float4 bv = *(const float4*)&bias[p * 16 + fl * 4];
    float4 s = make_float4(0.f, 0.f, 0.f, 0.f);
    for (int node = root + wid; node < nend; node += 8) {
        int cnt = min(cnt_col[node], CAP);
        const int* row = ell + (long)node * CAP;
        float4 acc = make_float4(0.f, 0.f, 0.f, 0.f);
        for (int j = slot; j < cnt; j += 16) {
            int r = row[j];
            uint2 hv = *(const uint2*)&tab[(long)r * 16 + fl * 4];
            acc.x += blo(hv.x); acc.y += bhi(hv.x);
            acc.z += blo(hv.y); acc.w += bhi(hv.y);
        }
#pragma unroll
        for (int m = 4; m <= 32; m <<= 1) {
            acc.x += __shfl_xor(acc.x, m, 64);
            acc.y += __shfl_xor(acc.y, m, 64);
            acc.z += __shfl_xor(acc.z, m, 64);
            acc.w += __shfl_xor(acc.w, m, 64);
        }
        // every lane now holds the slot-total for its fl (16 identical copies)
        float dc = dis[node];
        uint2 hv = *(const uint2*)&tab[(long)node * 16 + fl * 4];
        s.x += fmaxf(fmaf(dc, acc.x + blo(hv.x), bv.x), 0.f);
        s.y += fmaxf(fmaf(dc, acc.y + bhi(hv.x), bv.y), 0.f);
        s.z += fmaxf(fmaf(dc, acc.z + blo(hv.y), bv.z), 0.f);
        s.w += fmaxf(fmaf(dc, acc.w + bhi(hv.y), bv.w), 0.f);
    }
    if (lane < 4) *(float4*)&ls[wid][lane * 4] = s;
    __syncthreads();
    if (threadIdx.x < 16) {
        int t = threadIdx.x;
        float v = ls[0][t] + ls[1][t] + ls[2][t] + ls[3][t] +
                  ls[4][t] + ls[5][t] + ls[6][t] + ls[7][t];
        out[(long)g * CAT_F + p * 16 + t] = v / (float)(nend - root);
        out[(long)g * CAT_F + 64 + p * 16 + t] = x2[(long)root * 64 + p * 16 + t];
    }
}

// ---------------------------------------------------------------------------
extern "C" void kernel_launch(void* const* d_in, const int* in_sizes, int n_in,
                              void* d_out, int out_size, void* d_ws, size_t ws_size,
                              hipStream_t stream) {
    const float* x  = (const float*)d_in[0];
    const void*  ei = d_in[1];
    const void*  bt = d_in[2];
    const float* w1 = (const float*)d_in[3];
    const float* b1 = (const float*)d_in[4];
    const float* w2 = (const float*)d_in[5];
    const float* b2 = (const float*)d_in[6];
    float* out = (float*)d_out;

    const int N = in_sizes[0] / FEAT;     // 100000
    const int E = in_sizes[1] / 2;        // 1000000
    const int G = out_size / CAT_F;       // 500

    // workspace layout
    char* p = (char*)d_ws;
    size_t off = 0;
    auto alloc = [&](size_t bytes) {
        void* q = p + off;
        off = (off + bytes + 255) & ~(size_t)255;
        return q;
    };
    int*   mode     = (int*)  alloc(sizeof(int));
    int*   batch32  = (int*)  alloc((size_t)N * sizeof(int));
    int*   deg_cnt  = (int*)  alloc((size_t)N * sizeof(int));
    float* dis      = (float*)alloc((size_t)N * sizeof(float));
    int*   cnt_col  = (int*)  alloc((size_t)N * sizeof(int));
    int*   ell      = (int*)  alloc((size_t)N * CAP * sizeof(int));
    int*   root_idx = (int*)  alloc((size_t)(G + 1) * sizeof(int));
    float* rootc    = (float*)alloc((size_t)G * FEAT * sizeof(float));
    unsigned short* hq = (unsigned short*)alloc((size_t)N * FEAT * sizeof(unsigned short));
    float* x2       = (float*)alloc((size_t)N * FEAT * sizeof(float));
    (void)ws_size; (void)n_in;

    hipMemsetAsync(deg_cnt, 0, (size_t)N * sizeof(int), stream);
    hipMemsetAsync(cnt_col, 0, (size_t)N * sizeof(int), stream);

    detect_kernel<<<1, 1, 0, stream>>>((const unsigned int*)ei, mode);
    batch_prep<<<(N + 255) / 256, 256, 0, stream>>>(bt, mode, batch32, root_idx, N, G);

    // mega: [ell | gemm1 (unscaled) | rootc]
    const int eb = (E + 255) / 256;
    const int gb = (N + 63) / 64;
    const int rb = (G * FEAT + 255) / 256;
    mega1<<<eb + gb + rb, 256, 0, stream>>>(ei, mode, deg_cnt, cnt_col, ell, E,
                                            x, w1, hq, w2 + FEAT * FEAT, root_idx,
                                            rootc, N, G, eb, gb);

    // dis + in-place prescale of h1 quarters
    prep_prescale<<<dim3((N + 255) / 256, 4), 256, 0, stream>>>(deg_cnt, hq, dis, N);

    // conv1 aggregation: 4 feature-quarter passes (L2-resident gather table)
    const int agg_blocks = (N + 3) / 4;
    for (int pass = 0; pass < 4; ++pass)
        agg1_pass<<<agg_blocks, 256, 0, stream>>>(hq, dis, cnt_col, ell, b1, x2, N, pass);

    // conv2 transform: hq = bf16(dis * (relu(x2) @ w2lo + rootc[batch]))
    gemm2_kernel<<<gb, 256, 0, stream>>>(x2, w2, rootc, batch32, dis, hq, N);

    // conv2 aggregation + per-graph mean + root concat: 4 quarter passes
    for (int pass = 0; pass < 4; ++pass)
        agg2_pass<<<G, 512, 0, stream>>>(hq, dis, cnt_col, ell, b2, root_idx, x2, out, N, pass);
}

// Round 9
// 395.165 us; speedup vs baseline: 4.5280x; 4.5280x over previous
//
#include <hip/hip_runtime.h>
#include <hip/hip_bf16.h>

// Problem constants (from reference)
#define FEAT 64          // IN_F = HID_F = OUT_F
#define CAT_F 128        // HID_F + IN_F
#define CAP   64         // ELL capacity; deg ~ Poisson(10), P(deg>64) ~ 0

// bf16 helpers: u32 holds 2 bf16 (low ushort = even elem, high = odd elem)
__device__ inline float blo(unsigned u) { union { unsigned x; float f; } v; v.x = u << 16; return v.f; }
__device__ inline float bhi(unsigned u) { union { unsigned x; float f; } v; v.x = u & 0xFFFF0000u; return v.f; }
__device__ inline unsigned short f2b(float f) {
    union { float f; unsigned u; } v; v.f = f;
    unsigned r = v.u + 0x7FFFu + ((v.u >> 16) & 1u);
    return (unsigned short)(r >> 16);
}

// ---------------------------------------------------------------------------
__global__ void detect_kernel(const unsigned int* ei, int* mode) {
    *mode = (ei[1] == 0u && ei[3] == 0u && ei[5] == 0u && ei[7] == 0u) ? 1 : 0;
}

// batch convert + root boundaries (batch is sorted; every graph non-empty)
__global__ void batch_prep(const void* __restrict__ bt, const int* __restrict__ mode,
                           int* __restrict__ batch32, int* __restrict__ root_idx,
                           int N, int G) {
    int i = blockIdx.x * blockDim.x + threadIdx.x;
    if (i >= N) return;
    int m = *mode;
    int b = m ? (int)((const long long*)bt)[i] : ((const int*)bt)[i];
    batch32[i] = b;
    if (i == 0) { root_idx[0] = 0; root_idx[G] = N; }
    else {
        int bp = m ? (int)((const long long*)bt)[i - 1] : ((const int*)bt)[i - 1];
        if (b != bp) root_idx[b] = i;
    }
}

// Fused degree-count + ELL adjacency build (native edge dtype, wave-uniform branch)
__global__ void ell_build(const void* __restrict__ ei, const int* __restrict__ mode,
                          int* __restrict__ deg_cnt, int* __restrict__ cnt_col,
                          int* __restrict__ ell, int E) {
    int e = blockIdx.x * blockDim.x + threadIdx.x;
    if (e >= E) return;
    int r, c;
    if (*mode) {
        const long long* p = (const long long*)ei;
        r = (int)p[e]; c = (int)p[E + e];
    } else {
        const int* p = (const int*)ei;
        r = p[e]; c = p[E + e];
    }
    if (r != c) {
        atomicAdd(&deg_cnt[r], 1);
        int slot = atomicAdd(&cnt_col[c], 1);
        if (slot < CAP) ell[c * CAP + slot] = r;
    }
}

__global__ void dis_kernel(const int* __restrict__ deg_cnt, float* __restrict__ dis, int N) {
    int i = blockIdx.x * blockDim.x + threadIdx.x;
    if (i >= N) return;
    dis[i] = rsqrtf(1.0f + (float)deg_cnt[i]);   // deg >= 1 (self loop)
}

// ---------------------------------------------------------------------------
// Register-tiled GEMM (monolithic, round-4/5 proven structure):
//   hq[q][row][f16] = bf16( dis[row] * (op(A[row]) @ B + addv[batch[row]]) )
// Block: 64 rows x 64 cols, 256 threads, 4x4 micro-tile, full 64-k loop.
// LDS declared INSIDE the kernel (round-7/8 lesson: passing __shared__ tiles
// as pointer args to a __device__ body re-triggered the 64-VGPR spill).
// Named float4 locals only (round-3 lesson). __launch_bounds__(256,4).
template <int RELU_A, int ADDV>
__global__ __launch_bounds__(256, 4)
void gemm_tiled(const float* __restrict__ A, const float* __restrict__ B,
                const float* __restrict__ addv, const int* __restrict__ batch32,
                const float* __restrict__ dis, unsigned short* __restrict__ hq, int N) {
    __shared__ float AsT[64][68];   // [k][row]
    __shared__ float Bs[64][64];    // [k][col]
    const int tid = threadIdx.x;
    const long base = (long)blockIdx.x * 64;

#pragma unroll
    for (int u = 0; u < 4; ++u) {
        int v   = tid + u * 256;
        int row = v >> 4;
        int c4  = (v & 15) * 4;
        float4 bv = *(const float4*)&B[row * 64 + c4];
        *(float4*)&Bs[row][c4] = bv;
        float4 av = make_float4(0.f, 0.f, 0.f, 0.f);
        if (base + row < N) av = *(const float4*)&A[(base + row) * 64 + c4];
        if (RELU_A) {
            av.x = fmaxf(av.x, 0.f); av.y = fmaxf(av.y, 0.f);
            av.z = fmaxf(av.z, 0.f); av.w = fmaxf(av.w, 0.f);
        }
        AsT[c4 + 0][row] = av.x;
        AsT[c4 + 1][row] = av.y;
        AsT[c4 + 2][row] = av.z;
        AsT[c4 + 3][row] = av.w;
    }
    __syncthreads();

    const int c0 = (tid & 15) * 4;
    const int r0 = (tid >> 4) * 4;
    float4 acc0 = make_float4(0.f, 0.f, 0.f, 0.f);
    float4 acc1 = acc0, acc2 = acc0, acc3 = acc0;

#pragma unroll 4
    for (int k = 0; k < 64; ++k) {
        float4 bv = *(const float4*)&Bs[k][c0];
        float4 av = *(const float4*)&AsT[k][r0];
        acc0.x = fmaf(av.x, bv.x, acc0.x); acc0.y = fmaf(av.x, bv.y, acc0.y);
        acc0.z = fmaf(av.x, bv.z, acc0.z); acc0.w = fmaf(av.x, bv.w, acc0.w);
        acc1.x = fmaf(av.y, bv.x, acc1.x); acc1.y = fmaf(av.y, bv.y, acc1.y);
        acc1.z = fmaf(av.y, bv.z, acc1.z); acc1.w = fmaf(av.y, bv.w, acc1.w);
        acc2.x = fmaf(av.z, bv.x, acc2.x); acc2.y = fmaf(av.z, bv.y, acc2.y);
        acc2.z = fmaf(av.z, bv.z, acc2.z); acc2.w = fmaf(av.z, bv.w, acc2.w);
        acc3.x = fmaf(av.w, bv.x, acc3.x); acc3.y = fmaf(av.w, bv.y, acc3.y);
        acc3.z = fmaf(av.w, bv.z, acc3.z); acc3.w = fmaf(av.w, bv.w, acc3.w);
    }

    const long qbase = (long)(c0 >> 4) * N * 16 + (c0 & 15);
#define STORE_ROW(i, a)                                                       \
    {                                                                         \
        long row = base + r0 + (i);                                           \
        if (row < N) {                                                        \
            if (ADDV) {                                                       \
                int g = batch32[row];                                         \
                float4 adv = *(const float4*)&addv[(long)g * 64 + c0];        \
                a.x += adv.x; a.y += adv.y; a.z += adv.z; a.w += adv.w;       \
            }                                                                 \
            float s = dis[row];                                               \
            ushort4 o;                                                        \
            o.x = f2b(s * a.x); o.y = f2b(s * a.y);                           \
            o.z = f2b(s * a.z); o.w = f2b(s * a.w);                           \
            *(ushort4*)&hq[qbase + row * 16] = o;                             \
        }                                                                     \
    }
    STORE_ROW(0, acc0)
    STORE_ROW(1, acc1)
    STORE_ROW(2, acc2)
    STORE_ROW(3, acc3)
#undef STORE_ROW
}

// per-graph root contribution: rootc[g] = relu(x[root_g]) @ w2[64:128]  (fp32)
__global__ void rootc_kernel(const float* __restrict__ x, const float* __restrict__ w2hi,
                             const int* __restrict__ root_idx, float* __restrict__ rootc, int G) {
    int g = (blockIdx.x * blockDim.x + threadIdx.x) >> 6;
    int f = threadIdx.x & 63;
    if (g >= G) return;
    const float* xr = x + (long)root_idx[g] * 64;
    float acc = 0.f;
#pragma unroll
    for (int k = 0; k < 64; ++k)
        acc = fmaf(fmaxf(xr[k], 0.f), w2hi[k * 64 + f], acc);
    rootc[(long)g * 64 + f] = acc;
}

// ---------------------------------------------------------------------------
// Quartered conv1 aggregation pass p (table hq[p] = 3.2 MB -> per-XCD L2 resident):
//   x2[node][p*16+f] = dis[node]*(Sum_e hs_p[row_e][f] + hs_p[node][f]) + b1[f]
// wave per node; lane = slot(16) x fl(4); per edge 4 lanes x uint2 = one 32B sector
__global__ void agg1_pass(const unsigned short* __restrict__ hq, const float* __restrict__ dis,
                          const int* __restrict__ cnt_col, const int* __restrict__ ell,
                          const float* __restrict__ bias, float* __restrict__ x2,
                          int N, int p) {
    int node = (blockIdx.x * blockDim.x + threadIdx.x) >> 6;
    int lane = threadIdx.x & 63;
    if (node >= N) return;
    int slot = lane >> 2, fl = lane & 3;
    int cnt = min(cnt_col[node], CAP);
    const int* row = ell + (long)node * CAP;
    const unsigned short* tab = hq + (long)p * N * 16;
    float4 acc = make_float4(0.f, 0.f, 0.f, 0.f);
    for (int j = slot; j < cnt; j += 16) {
        int r = row[j];
        uint2 hv = *(const uint2*)&tab[(long)r * 16 + fl * 4];
        acc.x += blo(hv.x); acc.y += bhi(hv.x);
        acc.z += blo(hv.y); acc.w += bhi(hv.y);
    }
#pragma unroll
    for (int m = 4; m <= 32; m <<= 1) {
        acc.x += __shfl_xor(acc.x, m, 64);
        acc.y += __shfl_xor(acc.y, m, 64);
        acc.z += __shfl_xor(acc.z, m, 64);
        acc.w += __shfl_xor(acc.w, m, 64);
    }
    if (lane < 4) {
        float dc = dis[node];
        uint2 hv = *(const uint2*)&tab[(long)node * 16 + lane * 4];
        float4 bv = *(const float4*)&bias[p * 16 + lane * 4];
        float4 r;
        r.x = fmaf(dc, acc.x + blo(hv.x), bv.x);
        r.y = fmaf(dc, acc.y + bhi(hv.x), bv.y);
        r.z = fmaf(dc, acc.z + blo(hv.y), bv.z);
        r.w = fmaf(dc, acc.w + bhi(hv.y), bv.w);
        *(float4*)&x2[(long)node * 64 + p * 16 + lane * 4] = r;
    }
}

// Quartered conv2 aggregation pass p fused with per-graph mean + root concat:
//   out[g][p*16+f]    = mean_n relu(dis[n]*(Sum_e hs_p[r][f] + hs_p[n][f]) + b2[f])
//   out[g][64+p*16+f] = x2[root_g][p*16+f]
// block (512 thr = 8 waves) per graph
__global__ __launch_bounds__(512)
void agg2_pass(const unsigned short* __restrict__ hq, const float* __restrict__ dis,
               const int* __restrict__ cnt_col, const int* __restrict__ ell,
               const float* __restrict__ bias, const int* __restrict__ root_idx,
               const float* __restrict__ x2, float* __restrict__ out, int N, int p) {
    __shared__ float ls[8][16];
    int g = blockIdx.x;
    int root = root_idx[g], nend = root_idx[g + 1];
    int wid = threadIdx.x >> 6, lane = threadIdx.x & 63;
    int slot = lane >> 2, fl = lane & 3;
    const unsigned short* tab = hq + (long)p * N * 16;
    float4 bv = *(const float4*)&bias[p * 16 + fl * 4];
    float4 s = make_float4(0.f, 0.f, 0.f, 0.f);
    for (int node = root + wid; node < nend; node += 8) {
        int cnt = min(cnt_col[node], CAP);
        const int* row = ell + (long)node * CAP;
        float4 acc = make_float4(0.f, 0.f, 0.f, 0.f);
        for (int j = slot; j < cnt; j += 16) {
            int r = row[j];
            uint2 hv = *(const uint2*)&tab[(long)r * 16 + fl * 4];
            acc.x += blo(hv.x); acc.y += bhi(hv.x);
            acc.z += blo(hv.y); acc.w += bhi(hv.y);
        }
#pragma unroll
        for (int m = 4; m <= 32; m <<= 1) {
            acc.x += __shfl_xor(acc.x, m, 64);
            acc.y += __shfl_xor(acc.y, m, 64);
            acc.z += __shfl_xor(acc.z, m, 64);
            acc.w += __shfl_xor(acc.w, m, 64);
        }
        // every lane now holds the slot-total for its fl (16 identical copies)
        float dc = dis[node];
        uint2 hv = *(const uint2*)&tab[(long)node * 16 + fl * 4];
        s.x += fmaxf(fmaf(dc, acc.x + blo(hv.x), bv.x), 0.f);
        s.y += fmaxf(fmaf(dc, acc.y + bhi(hv.x), bv.y), 0.f);
        s.z += fmaxf(fmaf(dc, acc.z + blo(hv.y), bv.z), 0.f);
        s.w += fmaxf(fmaf(dc, acc.w + bhi(hv.y), bv.w), 0.f);
    }
    if (lane < 4) *(float4*)&ls[wid][lane * 4] = s;
    __syncthreads();
    if (threadIdx.x < 16) {
        int t = threadIdx.x;
        float v = ls[0][t] + ls[1][t] + ls[2][t] + ls[3][t] +
                  ls[4][t] + ls[5][t] + ls[6][t] + ls[7][t];
        out[(long)g * CAT_F + p * 16 + t] = v / (float)(nend - root);
        out[(long)g * CAT_F + 64 + p * 16 + t] = x2[(long)root * 64 + p * 16 + t];
    }
}

// ---------------------------------------------------------------------------
extern "C" void kernel_launch(void* const* d_in, const int* in_sizes, int n_in,
                              void* d_out, int out_size, void* d_ws, size_t ws_size,
                              hipStream_t stream) {
    const float* x  = (const float*)d_in[0];
    const void*  ei = d_in[1];
    const void*  bt = d_in[2];
    const float* w1 = (const float*)d_in[3];
    const float* b1 = (const float*)d_in[4];
    const float* w2 = (const float*)d_in[5];
    const float* b2 = (const float*)d_in[6];
    float* out = (float*)d_out;

    const int N = in_sizes[0] / FEAT;     // 100000
    const int E = in_sizes[1] / 2;        // 1000000
    const int G = out_size / CAT_F;       // 500

    // workspace layout
    char* p = (char*)d_ws;
    size_t off = 0;
    auto alloc = [&](size_t bytes) {
        void* q = p + off;
        off = (off + bytes + 255) & ~(size_t)255;
        return q;
    };
    int*   mode     = (int*)  alloc(sizeof(int));
    int*   batch32  = (int*)  alloc((size_t)N * sizeof(int));
    int*   deg_cnt  = (int*)  alloc((size_t)N * sizeof(int));
    float* dis      = (float*)alloc((size_t)N * sizeof(float));
    int*   cnt_col  = (int*)  alloc((size_t)N * sizeof(int));
    int*   ell      = (int*)  alloc((size_t)N * CAP * sizeof(int));
    int*   root_idx = (int*)  alloc((size_t)(G + 1) * sizeof(int));
    float* rootc    = (float*)alloc((size_t)G * FEAT * sizeof(float));
    unsigned short* hq = (unsigned short*)alloc((size_t)N * FEAT * sizeof(unsigned short));
    float* x2       = (float*)alloc((size_t)N * FEAT * sizeof(float));
    (void)ws_size; (void)n_in;

    hipMemsetAsync(deg_cnt, 0, (size_t)N * sizeof(int), stream);
    hipMemsetAsync(cnt_col, 0, (size_t)N * sizeof(int), stream);

    detect_kernel<<<1, 1, 0, stream>>>((const unsigned int*)ei, mode);
    batch_prep<<<(N + 255) / 256, 256, 0, stream>>>(bt, mode, batch32, root_idx, N, G);

    // CSR(ELL) build + degrees, then dis
    ell_build<<<(E + 255) / 256, 256, 0, stream>>>(ei, mode, deg_cnt, cnt_col, ell, E);
    dis_kernel<<<(N + 255) / 256, 256, 0, stream>>>(deg_cnt, dis, N);

    const int gb = (N + 63) / 64;
    const int agg_blocks = (N + 3) / 4;

    // rootc (independent of convs; needs only x + root_idx)
    rootc_kernel<<<(G + 3) / 4, 256, 0, stream>>>(x, w2 + FEAT * FEAT, root_idx, rootc, G);

    // conv1: hq = bf16(dis * (x @ w1)) blocked; x2 = agg(hq) + b1
    gemm_tiled<0, 0><<<gb, 256, 0, stream>>>(x, w1, nullptr, nullptr, dis, hq, N);
    for (int pass = 0; pass < 4; ++pass)
        agg1_pass<<<agg_blocks, 256, 0, stream>>>(hq, dis, cnt_col, ell, b1, x2, N, pass);

    // conv2: hq = bf16(dis * (relu(x2) @ w2lo + rootc[batch])) blocked
    gemm_tiled<1, 1><<<gb, 256, 0, stream>>>(x2, w2, rootc, batch32, dis, hq, N);

    // conv2 aggregation + per-graph mean + root concat: 4 quarter passes
    for (int pass = 0; pass < 4; ++pass)
        agg2_pass<<<G, 512, 0, stream>>>(hq, dis, cnt_col, ell, b2, root_idx, x2, out, N, pass);
}

// Round 10
// 227.824 us; speedup vs baseline: 7.8539x; 1.7345x over previous
//
#include <hip/hip_runtime.h>
#include <hip/hip_bf16.h>

// Problem constants (from reference)
#define FEAT 64          // IN_F = HID_F = OUT_F
#define CAT_F 128        // HID_F + IN_F
#define CAP   64         // ELL capacity; deg ~ Poisson(10), P(deg>64) ~ 0

// bf16 helpers
__device__ inline float blo(unsigned u) { union { unsigned x; float f; } v; v.x = u << 16; return v.f; }
__device__ inline unsigned short f2b(float f) {
    union { float f; unsigned u; } v; v.f = f;
    unsigned r = v.u + 0x7FFFu + ((v.u >> 16) & 1u);
    return (unsigned short)(r >> 16);
}

// ---------------------------------------------------------------------------
__global__ void detect_kernel(const unsigned int* ei, int* mode) {
    *mode = (ei[1] == 0u && ei[3] == 0u && ei[5] == 0u && ei[7] == 0u) ? 1 : 0;
}

// batch convert + root boundaries (batch is sorted; every graph non-empty)
__global__ void batch_prep(const void* __restrict__ bt, const int* __restrict__ mode,
                           int* __restrict__ batch32, int* __restrict__ root_idx,
                           int N, int G) {
    int i = blockIdx.x * blockDim.x + threadIdx.x;
    if (i >= N) return;
    int m = *mode;
    int b = m ? (int)((const long long*)bt)[i] : ((const int*)bt)[i];
    batch32[i] = b;
    if (i == 0) { root_idx[0] = 0; root_idx[G] = N; }
    else {
        int bp = m ? (int)((const long long*)bt)[i - 1] : ((const int*)bt)[i - 1];
        if (b != bp) root_idx[b] = i;
    }
}

// Fused degree-count + ELL adjacency build (native edge dtype, wave-uniform branch)
__global__ void ell_build(const void* __restrict__ ei, const int* __restrict__ mode,
                          int* __restrict__ deg_cnt, int* __restrict__ cnt_col,
                          int* __restrict__ ell, int E) {
    int e = blockIdx.x * blockDim.x + threadIdx.x;
    if (e >= E) return;
    int r, c;
    if (*mode) {
        const long long* p = (const long long*)ei;
        r = (int)p[e]; c = (int)p[E + e];
    } else {
        const int* p = (const int*)ei;
        r = p[e]; c = p[E + e];
    }
    if (r != c) {
        atomicAdd(&deg_cnt[r], 1);
        int slot = atomicAdd(&cnt_col[c], 1);
        if (slot < CAP) ell[c * CAP + slot] = r;
    }
}

__global__ void dis_kernel(const int* __restrict__ deg_cnt, float* __restrict__ dis, int N) {
    int i = blockIdx.x * blockDim.x + threadIdx.x;
    if (i >= N) return;
    dis[i] = rsqrtf(1.0f + (float)deg_cnt[i]);   // deg >= 1 (self loop)
}

// ---------------------------------------------------------------------------
// Register-tiled GEMM (monolithic, proven structure):
//   hs[row][f] = bf16( dis[row] * (op(A[row]) @ B + addv[batch[row]]) )
// 64x64 tile, 256 threads, 4x4 micro-tile, full 64-k loop. LDS inside the
// kernel (round-7/8 lesson), named float4 locals only (round-3 lesson),
// __launch_bounds__(256,4) for the 128-VGPR budget.
template <int RELU_A, int ADDV>
__global__ __launch_bounds__(256, 4)
void gemm_tiled(const float* __restrict__ A, const float* __restrict__ B,
                const float* __restrict__ addv, const int* __restrict__ batch32,
                const float* __restrict__ dis, unsigned short* __restrict__ hs, int N) {
    __shared__ float AsT[64][68];   // [k][row]
    __shared__ float Bs[64][64];    // [k][col]
    const int tid = threadIdx.x;
    const long base = (long)blockIdx.x * 64;

#pragma unroll
    for (int u = 0; u < 4; ++u) {
        int v   = tid + u * 256;
        int row = v >> 4;
        int c4  = (v & 15) * 4;
        float4 bv = *(const float4*)&B[row * 64 + c4];
        *(float4*)&Bs[row][c4] = bv;
        float4 av = make_float4(0.f, 0.f, 0.f, 0.f);
        if (base + row < N) av = *(const float4*)&A[(base + row) * 64 + c4];
        if (RELU_A) {
            av.x = fmaxf(av.x, 0.f); av.y = fmaxf(av.y, 0.f);
            av.z = fmaxf(av.z, 0.f); av.w = fmaxf(av.w, 0.f);
        }
        AsT[c4 + 0][row] = av.x;
        AsT[c4 + 1][row] = av.y;
        AsT[c4 + 2][row] = av.z;
        AsT[c4 + 3][row] = av.w;
    }
    __syncthreads();

    const int c0 = (tid & 15) * 4;
    const int r0 = (tid >> 4) * 4;
    float4 acc0 = make_float4(0.f, 0.f, 0.f, 0.f);
    float4 acc1 = acc0, acc2 = acc0, acc3 = acc0;

#pragma unroll 4
    for (int k = 0; k < 64; ++k) {
        float4 bv = *(const float4*)&Bs[k][c0];
        float4 av = *(const float4*)&AsT[k][r0];
        acc0.x = fmaf(av.x, bv.x, acc0.x); acc0.y = fmaf(av.x, bv.y, acc0.y);
        acc0.z = fmaf(av.x, bv.z, acc0.z); acc0.w = fmaf(av.x, bv.w, acc0.w);
        acc1.x = fmaf(av.y, bv.x, acc1.x); acc1.y = fmaf(av.y, bv.y, acc1.y);
        acc1.z = fmaf(av.y, bv.z, acc1.z); acc1.w = fmaf(av.y, bv.w, acc1.w);
        acc2.x = fmaf(av.z, bv.x, acc2.x); acc2.y = fmaf(av.z, bv.y, acc2.y);
        acc2.z = fmaf(av.z, bv.z, acc2.z); acc2.w = fmaf(av.z, bv.w, acc2.w);
        acc3.x = fmaf(av.w, bv.x, acc3.x); acc3.y = fmaf(av.w, bv.y, acc3.y);
        acc3.z = fmaf(av.w, bv.z, acc3.z); acc3.w = fmaf(av.w, bv.w, acc3.w);
    }

#define STORE_ROW(i, a)                                                       \
    {                                                                         \
        long row = base + r0 + (i);                                           \
        if (row < N) {                                                        \
            if (ADDV) {                                                       \
                int g = batch32[row];                                         \
                float4 adv = *(const float4*)&addv[(long)g * 64 + c0];        \
                a.x += adv.x; a.y += adv.y; a.z += adv.z; a.w += adv.w;       \
            }                                                                 \
            float s = dis[row];                                               \
            ushort4 o;                                                        \
            o.x = f2b(s * a.x); o.y = f2b(s * a.y);                           \
            o.z = f2b(s * a.z); o.w = f2b(s * a.w);                           \
            *(ushort4*)&hs[row * 64 + c0] = o;                                \
        }                                                                     \
    }
    STORE_ROW(0, acc0)
    STORE_ROW(1, acc1)
    STORE_ROW(2, acc2)
    STORE_ROW(3, acc3)
#undef STORE_ROW
}

// per-graph root contribution: rootc[g] = relu(x[root_g]) @ w2[64:128]  (fp32)
__global__ void rootc_kernel(const float* __restrict__ x, const float* __restrict__ w2hi,
                             const int* __restrict__ root_idx, float* __restrict__ rootc, int G) {
    int g = (blockIdx.x * blockDim.x + threadIdx.x) >> 6;
    int f = threadIdx.x & 63;
    if (g >= G) return;
    const float* xr = x + (long)root_idx[g] * 64;
    float acc = 0.f;
#pragma unroll
    for (int k = 0; k < 64; ++k)
        acc = fmaf(fmaxf(xr[k], 0.f), w2hi[k * 64 + f], acc);
    rootc[(long)g * 64 + f] = acc;
}

// ---------------------------------------------------------------------------
// Per-node gather sum over prescaled rows: acc[f] = Sum_e hs[row_e][f].
// lane = feature; edge ids pre-loaded into rv (one coalesced read) and
// broadcast with __shfl; 4-batched independent 128B wave-loads for MLP.
// Returns the fp32 sum for this lane's feature.
__device__ inline float gather_sum(const unsigned short* __restrict__ hs,
                                   const int* __restrict__ row, int cnt, int lane) {
    int rv = (lane < cnt) ? row[lane] : 0;
    float acc = 0.f;
    int j = 0;
    for (; j + 4 <= cnt; j += 4) {
        int r0 = __shfl(rv, j,     64);
        int r1 = __shfl(rv, j + 1, 64);
        int r2 = __shfl(rv, j + 2, 64);
        int r3 = __shfl(rv, j + 3, 64);
        float v0 = blo(hs[r0 * 64 + lane]);
        float v1 = blo(hs[r1 * 64 + lane]);
        float v2 = blo(hs[r2 * 64 + lane]);
        float v3 = blo(hs[r3 * 64 + lane]);
        acc += v0; acc += v1; acc += v2; acc += v3;
    }
    for (; j < cnt; ++j) {
        int r = __shfl(rv, j, 64);
        acc += blo(hs[r * 64 + lane]);
    }
    return acc;
}

// conv1 aggregation: x2[node][f] = dis[node]*(Sum + hs[node][f]) + b1[f]
// wave per node, lane = feature (all 64 lanes active, coalesced store)
__global__ void agg1_kernel(const unsigned short* __restrict__ hs, const float* __restrict__ dis,
                            const int* __restrict__ cnt_col, const int* __restrict__ ell,
                            const float* __restrict__ bias, float* __restrict__ x2, int N) {
    int node = (blockIdx.x * blockDim.x + threadIdx.x) >> 6;
    int lane = threadIdx.x & 63;
    if (node >= N) return;
    int cnt = min(cnt_col[node], CAP);
    float acc = gather_sum(hs, ell + (long)node * CAP, cnt, lane);
    float dc = dis[node];
    float self = blo(hs[node * 64 + lane]);
    x2[(long)node * 64 + lane] = fmaf(dc, acc + self, bias[lane]);
}

// conv2 aggregation partials: graph g split into 4 chunks; block (4 waves)
// per chunk accumulates Sum_n relu(dis[n]*(Sum_e + self) + b2) over its nodes.
__global__ __launch_bounds__(256)
void agg2_part(const unsigned short* __restrict__ hs, const float* __restrict__ dis,
               const int* __restrict__ cnt_col, const int* __restrict__ ell,
               const float* __restrict__ bias, const int* __restrict__ root_idx,
               float* __restrict__ partial) {
    __shared__ float ls[4][64];
    int g  = blockIdx.x >> 2;
    int ch = blockIdx.x & 3;
    int root = root_idx[g], nend = root_idx[g + 1];
    int len = nend - root;
    int chunk = (len + 3) >> 2;
    int start = root + ch * chunk;
    int end   = min(start + chunk, nend);
    int wid  = threadIdx.x >> 6;
    int lane = threadIdx.x & 63;
    float bv = bias[lane];
    float s = 0.f;
    for (int node = start + wid; node < end; node += 4) {
        int cnt = min(cnt_col[node], CAP);
        float acc = gather_sum(hs, ell + (long)node * CAP, cnt, lane);
        float dc = dis[node];
        float self = blo(hs[node * 64 + lane]);
        s += fmaxf(fmaf(dc, acc + self, bv), 0.f);
    }
    ls[wid][lane] = s;
    __syncthreads();
    if (threadIdx.x < 64) {
        float v = ls[0][threadIdx.x] + ls[1][threadIdx.x] +
                  ls[2][threadIdx.x] + ls[3][threadIdx.x];
        partial[(long)blockIdx.x * 64 + threadIdx.x] = v;
    }
}

// final: out[g][0:64] = (Sum of 4 chunk partials)/len ; out[g][64:128] = x2[root]
__global__ void final_reduce(const float* __restrict__ partial, const int* __restrict__ root_idx,
                             const float* __restrict__ x2, float* __restrict__ out) {
    int g = blockIdx.x;
    int f = threadIdx.x;    // 64
    int root = root_idx[g];
    int len  = root_idx[g + 1] - root;
    const float* p = partial + (long)g * 4 * 64;
    float v = p[f] + p[64 + f] + p[128 + f] + p[192 + f];
    out[(long)g * CAT_F + f] = v / (float)len;
    out[(long)g * CAT_F + 64 + f] = x2[(long)root * 64 + f];
}

// ---------------------------------------------------------------------------
extern "C" void kernel_launch(void* const* d_in, const int* in_sizes, int n_in,
                              void* d_out, int out_size, void* d_ws, size_t ws_size,
                              hipStream_t stream) {
    const float* x  = (const float*)d_in[0];
    const void*  ei = d_in[1];
    const void*  bt = d_in[2];
    const float* w1 = (const float*)d_in[3];
    const float* b1 = (const float*)d_in[4];
    const float* w2 = (const float*)d_in[5];
    const float* b2 = (const float*)d_in[6];
    float* out = (float*)d_out;

    const int N = in_sizes[0] / FEAT;     // 100000
    const int E = in_sizes[1] / 2;        // 1000000
    const int G = out_size / CAT_F;       // 500

    // workspace layout
    char* p = (char*)d_ws;
    size_t off = 0;
    auto alloc = [&](size_t bytes) {
        void* q = p + off;
        off = (off + bytes + 255) & ~(size_t)255;
        return q;
    };
    int*   mode     = (int*)  alloc(sizeof(int));
    int*   batch32  = (int*)  alloc((size_t)N * sizeof(int));
    int*   deg_cnt  = (int*)  alloc((size_t)N * sizeof(int));
    float* dis      = (float*)alloc((size_t)N * sizeof(float));
    int*   cnt_col  = (int*)  alloc((size_t)N * sizeof(int));
    int*   ell      = (int*)  alloc((size_t)N * CAP * sizeof(int));
    int*   root_idx = (int*)  alloc((size_t)(G + 1) * sizeof(int));
    float* rootc    = (float*)alloc((size_t)G * FEAT * sizeof(float));
    unsigned short* hs = (unsigned short*)alloc((size_t)N * FEAT * sizeof(unsigned short));
    float* x2       = (float*)alloc((size_t)N * FEAT * sizeof(float));
    float* partial  = (float*)alloc((size_t)G * 4 * FEAT * sizeof(float));
    (void)ws_size; (void)n_in;

    hipMemsetAsync(deg_cnt, 0, (size_t)N * sizeof(int), stream);
    hipMemsetAsync(cnt_col, 0, (size_t)N * sizeof(int), stream);

    detect_kernel<<<1, 1, 0, stream>>>((const unsigned int*)ei, mode);
    batch_prep<<<(N + 255) / 256, 256, 0, stream>>>(bt, mode, batch32, root_idx, N, G);

    // CSR(ELL) build + degrees, then dis
    ell_build<<<(E + 255) / 256, 256, 0, stream>>>(ei, mode, deg_cnt, cnt_col, ell, E);
    dis_kernel<<<(N + 255) / 256, 256, 0, stream>>>(deg_cnt, dis, N);

    const int gb = (N + 63) / 64;
    const int agg_blocks = (N + 3) / 4;

    // rootc (independent of convs; needs only x + root_idx)
    rootc_kernel<<<(G + 3) / 4, 256, 0, stream>>>(x, w2 + FEAT * FEAT, root_idx, rootc, G);

    // conv1: hs = bf16(dis * (x @ w1)) ; x2 = agg(hs) + b1
    gemm_tiled<0, 0><<<gb, 256, 0, stream>>>(x, w1, nullptr, nullptr, dis, hs, N);
    agg1_kernel<<<agg_blocks, 256, 0, stream>>>(hs, dis, cnt_col, ell, b1, x2, N);

    // conv2: hs = bf16(dis * (relu(x2) @ w2lo + rootc[batch]))
    gemm_tiled<1, 1><<<gb, 256, 0, stream>>>(x2, w2, rootc, batch32, dis, hs, N);

    // conv2 aggregation partials (4 chunks per graph) + deterministic reduce
    agg2_part<<<G * 4, 256, 0, stream>>>(hs, dis, cnt_col, ell, b2, root_idx, partial);
    final_reduce<<<G, 64, 0, stream>>>(partial, root_idx, x2, out);
}